// Round 1
// baseline (3478.229 us; speedup 1.0000x reference)
//
#include <hip/hip_runtime.h>
#include <math.h>

#define N_ 4
#define C_ 31
#define H_ 128
#define W_ 128
#define NW_ 65
#define TOTAL (N_*C_*H_*W_)
#define NROWS (N_*C_*H_)
#define PI_F 3.14159265358979f
#define RHO_F 1.05f
#define INV_RHO (1.0f/1.05f)

__device__ __forceinline__ float2 cmul(float2 a, float2 b){
  return make_float2(a.x*b.x - a.y*b.y, a.x*b.y + a.y*b.x);
}

__device__ __forceinline__ float shrinkf(float x, float t){
  return copysignf(fmaxf(fabsf(x) - t, 0.0f), x);
}

__device__ __forceinline__ void setup_tw128(float2* tw, int tid){
  float sv, cv;
  sincosf(-2.0f * PI_F * (float)tid / 128.0f, &sv, &cv);
  tw[tid] = make_float2(cv, sv);
}

// In-LDS 128-point complex FFT, 64 threads, radix-2 DIT with bit-reversal.
// SIGN = -1 forward (e^{-i}), +1 inverse (no normalization applied here).
template<int SIGN>
__device__ __forceinline__ void fft128_lds(float2* s, const float2* tw, int tid){
  __syncthreads();
  #pragma unroll
  for (int e = 0; e < 2; ++e){
    int i = tid + e*64;
    int j = __brev(i) >> 25;           // 7-bit reverse
    if (i < j){ float2 a = s[i]; float2 b = s[j]; s[i] = b; s[j] = a; }
  }
  __syncthreads();
  #pragma unroll
  for (int st = 1; st <= 7; ++st){
    int hm = 1 << (st-1);
    int j  = tid & (hm-1);
    int i0 = ((tid >> (st-1)) << st) + j;
    int i1 = i0 + hm;
    float2 w = tw[j << (7-st)];
    if (SIGN > 0) w.y = -w.y;
    float2 u = s[i0];
    float2 t = cmul(w, s[i1]);
    s[i0] = make_float2(u.x + t.x, u.y + t.y);
    s[i1] = make_float2(u.x - t.x, u.y - t.y);
    __syncthreads();
  }
}

// K1: update Vh,Vv,Vs in place (pointwise in V, neighbor reads of Z).
__global__ __launch_bounds__(256) void kern_V(const float* __restrict__ Z,
    float* __restrict__ Vh, float* __restrict__ Vv, float* __restrict__ Vs,
    float thr, int first)
{
  int idx = blockIdx.x * 256 + threadIdx.x;
  if (idx >= TOTAL) return;
  int w = idx & (W_-1);
  int h = (idx >> 7) & (H_-1);
  int nc = idx >> 14;
  int c = nc % C_;
  float z = Z[idx];
  int iw1 = (idx - w) + ((w+1) & (W_-1));
  int ih1 = (idx - (h<<7)) + (((h+1) & (H_-1)) << 7);
  int ic1 = (c == C_-1) ? idx - (C_-1)*(H_*W_) : idx + H_*W_;
  float Dh = z - Z[iw1];
  float Dv = z - Z[ih1];
  float Ds = z - Z[ic1];
  if (first){
    Vh[idx] = shrinkf(Dh, thr);
    Vv[idx] = shrinkf(Dv, thr);
    Vs[idx] = shrinkf(Ds, thr);
  } else {
    const float a = 1.0f + INV_RHO;
    float vh = Vh[idx], vv = Vv[idx], vs = Vs[idx];
    Vh[idx] = shrinkf(a*Dh - vh*INV_RHO, thr) + (vh - Dh)*INV_RHO;
    Vv[idx] = shrinkf(a*Dv - vv*INV_RHO, thr) + (vv - Dv)*INV_RHO;
    Vs[idx] = shrinkf(a*Ds - vs*INV_RHO, thr) + (vs - Ds)*INV_RHO;
  }
}

// K2: numer' = Q + dhT(Vh)+dvT(Vv)+dsT(Vs), then R2C FFT-128 along W (keep 65 bins).
__global__ __launch_bounds__(64) void kern_fwdW(const float* __restrict__ Q,
    const float* __restrict__ Vh, const float* __restrict__ Vv, const float* __restrict__ Vs,
    float2* __restrict__ A)
{
  __shared__ float2 sp[128];
  __shared__ float2 tw[64];
  int tid = threadIdx.x;
  setup_tw128(tw, tid);
  int row = blockIdx.x;           // (n*C + c)*H + h
  int h  = row & (H_-1);
  int nc = row >> 7;
  int c  = nc % C_;
  int n  = nc / C_;
  long base = (long)row * W_;
  int hm1 = (h + H_-1) & (H_-1);
  long base_v = ((long)nc * H_ + hm1) * W_;
  int cm1 = (c == 0) ? (C_-1) : (c-1);
  long base_s = (((long)n * C_ + cm1) * H_ + h) * W_;
  #pragma unroll
  for (int e = 0; e < 2; ++e){
    int w = tid + e*64;
    int wm1 = (w + W_-1) & (W_-1);
    float nm = Q[base + w]
      + (Vh[base + w] - Vh[base + wm1])
      + (Vv[base + w] - Vv[base_v + w])
      + (Vs[base + w] - Vs[base_s + w]);
    sp[w] = make_float2(nm, 0.0f);
  }
  fft128_lds<-1>(sp, tw, tid);
  float2* Arow = A + (long)row * NW_;
  Arow[tid] = sp[tid];
  if (tid == 0) Arow[64] = sp[64];
}

// K3/K5: C2C FFT-128 along H, in place. SIGN=-1 fwd, +1 inv (applies 1/128).
template<int SIGN>
__global__ __launch_bounds__(64) void kern_fftH(float2* __restrict__ A)
{
  __shared__ float2 sp[128];
  __shared__ float2 tw[64];
  int tid = threadIdx.x;
  setup_tw128(tw, tid);
  int bid = blockIdx.x;           // nc*65 + wp
  int wp = bid % NW_;
  int nc = bid / NW_;
  float2* base = A + (long)nc * H_ * NW_ + wp;
  sp[tid]      = base[(long)tid * NW_];
  sp[tid + 64] = base[(long)(tid + 64) * NW_];
  fft128_lds<SIGN>(sp, tw, tid);
  const float sc = (SIGN > 0) ? (1.0f/128.0f) : 1.0f;
  float2 r0 = sp[tid], r1 = sp[tid + 64];
  base[(long)tid * NW_]        = make_float2(r0.x*sc, r0.y*sc);
  base[(long)(tid + 64) * NW_] = make_float2(r1.x*sc, r1.y*sc);
}

// K4: along C (length 31, prime): fwd DFT-31 -> scale by 1/(1+demo) -> inv DFT-31 (1/31).
__global__ __launch_bounds__(64) void kern_solveC(float2* __restrict__ A)
{
  __shared__ float2 tw[31];           // exp(-2*pi*i*m/31)
  __shared__ float2 ybuf[31*64];      // [k][tid]
  int tid = threadIdx.x;
  if (tid < 31){
    float sv, cv;
    sincosf(-2.0f * PI_F * (float)tid / 31.0f, &sv, &cv);
    tw[tid] = make_float2(cv, sv);
  }
  __syncthreads();
  int nh = blockIdx.x;                // n*128 + h
  int wp = blockIdx.y * 64 + tid;
  int n = nh >> 7, h = nh & (H_-1);
  if (wp >= NW_) return;
  float2* base = A + (((long)n * C_) * H_ + h) * NW_ + wp;   // c stride = H_*NW_
  float2 x[31];
  #pragma unroll
  for (int j = 0; j < C_; ++j) x[j] = base[(long)j * H_ * NW_];
  float dh = 2.0f - 2.0f * cosf(2.0f * PI_F * (float)h  / 128.0f);
  float dw = 2.0f - 2.0f * cosf(2.0f * PI_F * (float)wp / 128.0f);
  for (int k = 0; k < C_; ++k){
    float2 acc = make_float2(0.0f, 0.0f);
    int m = 0;
    #pragma unroll
    for (int j = 0; j < C_; ++j){
      float2 t = tw[m];
      acc.x += x[j].x * t.x - x[j].y * t.y;
      acc.y += x[j].x * t.y + x[j].y * t.x;
      m += k; if (m >= C_) m -= C_;
    }
    float dcv = 2.0f - 2.0f * cosf(2.0f * PI_F * (float)k / 31.0f);
    float s = 1.0f / (1.0f + dcv + dh + dw);
    ybuf[k*64 + tid] = make_float2(acc.x * s, acc.y * s);
  }
  for (int j = 0; j < C_; ++j){
    float2 acc = make_float2(0.0f, 0.0f);
    int m = 0;
    #pragma unroll
    for (int k = 0; k < C_; ++k){
      float2 t = tw[m];                 // use conj(t) for inverse
      float2 y = ybuf[k*64 + tid];
      acc.x += y.x * t.x + y.y * t.y;
      acc.y += y.y * t.x - y.x * t.y;
      m += j; if (m >= C_) m -= C_;
    }
    base[(long)j * H_ * NW_] = make_float2(acc.x * (1.0f/31.0f), acc.y * (1.0f/31.0f));
  }
}

// K6: Hermitian-expand, inverse FFT-128 along W (1/128), write Z; fused X/G1/Q update.
__global__ __launch_bounds__(64) void kern_invW(const float2* __restrict__ A,
    float* __restrict__ Z, const float* __restrict__ Y, const float* __restrict__ inW,
    float* __restrict__ G1, float* __restrict__ Q,
    float mu, int first, int last)
{
  __shared__ float2 sp[128];
  __shared__ float2 tw[64];
  int tid = threadIdx.x;
  setup_tw128(tw, tid);
  int row = blockIdx.x;
  const float2* Arow = A + (long)row * NW_;
  float2 a = Arow[tid];
  sp[tid] = a;
  if (tid == 0) sp[64] = Arow[64];
  else          sp[128 - tid] = make_float2(a.x, -a.y);
  fft128_lds<1>(sp, tw, tid);
  long base = (long)row * W_;
  #pragma unroll
  for (int e = 0; e < 2; ++e){
    int w = tid + e*64;
    float z = sp[w].x * (1.0f/128.0f);
    long p = base + w;
    Z[p] = z;
    if (!last){
      float y = Y[p], iw = inW[p];
      float g1 = first ? 0.0f : G1[p];
      float x = (iw*y + mu*z - g1) / (iw + mu);
      float g1n = g1 + mu*(x - z);
      G1[p] = g1n;
      Q[p] = x + g1n / (mu * RHO_F);
    }
  }
}

extern "C" void kernel_launch(void* const* d_in, const int* in_sizes, int n_in,
                              void* d_out, int out_size, void* d_ws, size_t ws_size,
                              hipStream_t stream)
{
  const float* Y   = (const float*)d_in[0];
  const float* inW = (const float*)d_in[1];
  float* Z = (float*)d_out;

  float* Q  = (float*)d_ws;
  float* G1 = Q  + TOTAL;
  float* Vh = G1 + TOTAL;
  float* Vv = Vh + TOTAL;
  float* Vs = Vv + TOTAL;
  float2* A = (float2*)(Vs + TOTAL);   // 5*TOTAL*4 bytes in, 8B-aligned

  float mu = 0.1f;
  for (int it = 0; it < 20; ++it){
    int first = (it == 0) ? 1 : 0;
    int last  = (it == 19) ? 1 : 0;
    float thr = 0.1f / mu;             // lam/mu2
    const float* Zs = first ? Y : (const float*)Z;
    const float* Qs = first ? Y : (const float*)Q;

    kern_V<<<dim3(TOTAL/256), dim3(256), 0, stream>>>(Zs, Vh, Vv, Vs, thr, first);
    kern_fwdW<<<dim3(NROWS), dim3(64), 0, stream>>>(Qs, Vh, Vv, Vs, A);
    kern_fftH<-1><<<dim3(N_*C_*NW_), dim3(64), 0, stream>>>(A);
    kern_solveC<<<dim3(N_*H_, 2), dim3(64), 0, stream>>>(A);
    kern_fftH<1><<<dim3(N_*C_*NW_), dim3(64), 0, stream>>>(A);
    kern_invW<<<dim3(NROWS), dim3(64), 0, stream>>>(A, Z, Y, inW, G1, Q, mu, first, last);

    mu *= 1.05f;
  }
}

// Round 2
// 1643.677 us; speedup vs baseline: 2.1161x; 2.1161x over previous
//
#include <hip/hip_runtime.h>
#include <math.h>

#define N_ 4
#define C_ 31
#define H_ 128
#define W_ 128
#define TOTAL (N_*C_*H_*W_)
#define CH_ (C_*H_)            // 3968 complex rows per volume-pair
#define PI_F 3.14159265358979f
#define RHO_F 1.05f
#define INV_RHO (1.0f/1.05f)
#define NORM_F (1.0f/(31.0f*128.0f*128.0f))

__device__ __forceinline__ float2 cmul(float2 a, float2 b){
  return make_float2(a.x*b.x - a.y*b.y, a.x*b.y + a.y*b.x);
}
__device__ __forceinline__ float2 shflx(float2 v, int m){
  return make_float2(__shfl_xor(v.x, m, 64), __shfl_xor(v.y, m, 64));
}
__device__ __forceinline__ float shrinkf(float x, float t){
  return copysignf(fmaxf(fabsf(x) - t, 0.0f), x);
}

// Per-lane twiddles for the 64-lane shuffle FFT-128 (2 complex elems/lane).
// tw[0] = e^{sgn*2pi*i*t/128} (span-64 stage / final recombine).
// tw[i], i=1..6: stage span sp=64>>i. Forward (sel=true): only lanes with
// (t&sp) multiply, others get (1,0). Inverse (sel=false): all lanes get
// e^{sgn*2pi*i*(t&(sp-1))/(2sp)}.
__device__ __forceinline__ void make_tw(float2* tw, int t, float sgn, bool sel){
  float s, c;
  sincosf(sgn * 2.0f * PI_F * (float)t / 128.0f, &s, &c);
  tw[0] = make_float2(c, s);
  #pragma unroll
  for (int i = 1; i < 7; ++i){
    int sp = 64 >> i;
    float ang = (!sel || (t & sp)) ? sgn * 2.0f * PI_F * (float)(t & (sp-1)) / (float)(2*sp) : 0.0f;
    sincosf(ang, &s, &c);
    tw[i] = make_float2(c, s);
  }
}

// Forward DIF FFT-128: in a=x[t], b=x[t+64]; out positions p: a->p=t, b->p=t+64,
// holding X[bitrev7(p)]. twf from make_tw(sgn=-1, sel=true).
__device__ __forceinline__ void fft128_fwd(float2& a, float2& b, const float2* twf, int t){
  float2 u = make_float2(a.x + b.x, a.y + b.y);
  float2 d = make_float2(a.x - b.x, a.y - b.y);
  float2 v = cmul(d, twf[0]);
  #pragma unroll
  for (int i = 1; i < 7; ++i){
    int sp = 64 >> i;
    bool up = (t & sp) != 0;
    float2 pu = shflx(u, sp);
    float2 du = up ? make_float2(pu.x - u.x, pu.y - u.y)
                   : make_float2(u.x + pu.x, u.y + pu.y);
    u = cmul(du, twf[i]);
    float2 pv = shflx(v, sp);
    float2 dv = up ? make_float2(pv.x - v.x, pv.y - v.y)
                   : make_float2(v.x + pv.x, v.y + pv.y);
    v = cmul(dv, twf[i]);
  }
  a = u; b = v;
}

// Inverse DIT FFT-128 (unnormalized): consumes the bit-reversed positions,
// produces natural order a=x[t], b=x[t+64]. twi from make_tw(sgn=+1, sel=false).
__device__ __forceinline__ void fft128_inv(float2& a, float2& b, const float2* twi, int t){
  float2 u = a, v = b;
  #pragma unroll
  for (int i = 6; i >= 1; --i){
    int sp = 64 >> i;            // 1,2,4,8,16,32
    bool up = (t & sp) != 0;
    float2 pu = shflx(u, sp);
    float2 e  = up ? pu : u;
    float2 o  = up ? u  : pu;
    float2 wo = cmul(o, twi[i]);
    u = up ? make_float2(e.x - wo.x, e.y - wo.y)
           : make_float2(e.x + wo.x, e.y + wo.y);
    float2 pv = shflx(v, sp);
    float2 ev = up ? pv : v;
    float2 ov = up ? v  : pv;
    float2 wv = cmul(ov, twi[i]);
    v = up ? make_float2(ev.x - wv.x, ev.y - wv.y)
           : make_float2(ev.x + wv.x, ev.y + wv.y);
  }
  float2 tv = cmul(v, twi[0]);   // twi[0] = conj(w0)
  a = make_float2(u.x + tv.x, u.y + tv.y);
  b = make_float2(u.x - tv.x, u.y - tv.y);
}

// K1: V-field update (pointwise in V, +1 neighbor reads of Z).
__global__ __launch_bounds__(256) void kern_V(const float* __restrict__ Z,
    float* __restrict__ Vh, float* __restrict__ Vv, float* __restrict__ Vs,
    float thr, int first)
{
  int idx = blockIdx.x * 256 + threadIdx.x;
  int w = idx & (W_-1);
  int h = (idx >> 7) & (H_-1);
  int nc = idx >> 14;
  int c = nc % C_;
  float z = Z[idx];
  int iw1 = (idx - w) + ((w+1) & (W_-1));
  int ih1 = (idx - (h<<7)) + (((h+1) & (H_-1)) << 7);
  int ic1 = (c == C_-1) ? idx - (C_-1)*(H_*W_) : idx + H_*W_;
  float Dh = z - Z[iw1];
  float Dv = z - Z[ih1];
  float Ds = z - Z[ic1];
  if (first){
    Vh[idx] = shrinkf(Dh, thr);
    Vv[idx] = shrinkf(Dv, thr);
    Vs[idx] = shrinkf(Ds, thr);
  } else {
    const float a = 1.0f + INV_RHO;
    float vh = Vh[idx], vv = Vv[idx], vs = Vs[idx];
    Vh[idx] = shrinkf(a*Dh - vh*INV_RHO, thr) + (vh - Dh)*INV_RHO;
    Vv[idx] = shrinkf(a*Dv - vv*INV_RHO, thr) + (vv - Dv)*INV_RHO;
    Vs[idx] = shrinkf(a*Ds - vs*INV_RHO, thr) + (vs - Ds)*INV_RHO;
  }
}

// K2: numer for volume pair (2p, 2p+1) packed as complex; shuffle FFT-128 along W;
// scatter-store to A[pair][p_w][c][h].
__global__ __launch_bounds__(256) void kern_fwdW(const float* __restrict__ Q,
    const float* __restrict__ Vh, const float* __restrict__ Vv, const float* __restrict__ Vs,
    float2* __restrict__ A)
{
  int tid = threadIdx.x, lane = tid & 63;
  int r = blockIdx.x * 4 + (tid >> 6);       // complex-row id
  int pair = r / CH_;
  int ch = r - pair * CH_;
  int c = ch >> 7, h = ch & (H_-1);
  long b0 = (((long)(2*pair) * C_ + c) * H_ + h) * W_;
  long b1 = b0 + (long)C_ * H_ * W_;
  int hm1 = (h + H_-1) & (H_-1);
  int cm1 = (c == 0) ? (C_-1) : (c-1);
  long bv = b0 + ((long)hm1 - h) * W_;
  long bs = (((long)(2*pair) * C_ + cm1) * H_ + h) * W_;
  long dv = bv - b0, ds = bs - b0;

  float2 twf[7];
  make_tw(twf, lane, -1.0f, true);

  float2 ab[2];
  #pragma unroll
  for (int e = 0; e < 2; ++e){
    int w = lane + 64*e;
    int wm1 = (w + W_-1) & (W_-1);
    float re = Q[b0+w] + (Vh[b0+w] - Vh[b0+wm1]) + (Vv[b0+w] - Vv[b0+dv+w]) + (Vs[b0+w] - Vs[b0+ds+w]);
    float im = Q[b1+w] + (Vh[b1+w] - Vh[b1+wm1]) + (Vv[b1+w] - Vv[b1+dv+w]) + (Vs[b1+w] - Vs[b1+ds+w]);
    ab[e] = make_float2(re, im);
  }
  fft128_fwd(ab[0], ab[1], twf, lane);

  float2* dst = A + ((long)pair * W_) * CH_ + (long)c * H_ + h;
  dst[(long)lane * CH_]        = ab[0];
  dst[(long)(lane + 64) * CH_] = ab[1];
}

// K3: fused H-FFT fwd + C DFT-31/scale/iDFT-31 + H-FFT inv on a [C][H] slab.
// One block per (pair, w-position). All normalization folded into the scale.
__global__ __launch_bounds__(256) void kern_CH(float2* __restrict__ A)
{
  __shared__ float2 slab[C_][H_];
  __shared__ float2 ybuf[C_][H_];
  __shared__ float2 tw31[C_];
  __shared__ float  dcs[C_];
  int tid = threadIdx.x, lane = tid & 63, wv = tid >> 6;
  int bid = blockIdx.x;                 // pair*128 + wpos
  int wpos = bid & (W_-1);

  if (tid < C_){
    float s, c;
    sincosf(-2.0f * PI_F * (float)tid / 31.0f, &s, &c);
    tw31[tid] = make_float2(c, s);
    dcs[tid] = 2.0f - 2.0f * cosf(2.0f * PI_F * (float)tid / 31.0f);
  }
  float2 twf[7], twi[7];
  make_tw(twf, lane, -1.0f, true);
  make_tw(twi, lane, +1.0f, false);

  float2* g = A + (long)bid * CH_;
  for (int i = tid; i < CH_; i += 256)
    ((float2*)slab)[i] = g[i];
  __syncthreads();

  // H-FFT forward, 31 rows round-robin over 4 waves
  for (int c = wv; c < C_; c += 4){
    float2 a = slab[c][lane], b = slab[c][lane+64];
    fft128_fwd(a, b, twf, lane);
    slab[c][lane] = a; slab[c][lane+64] = b;
  }
  __syncthreads();

  // C-phase: thread = (column, k-half)
  int col = tid & (H_-1);
  int half = tid >> 7;
  int fh = __brev(col)  >> 25;
  int fw = __brev(wpos) >> 25;
  float dh = 2.0f - 2.0f * cosf(2.0f * PI_F * (float)fh / 128.0f);
  float dw = 2.0f - 2.0f * cosf(2.0f * PI_F * (float)fw / 128.0f);
  float base = 1.0f + dh + dw;

  float2 x[C_];
  #pragma unroll
  for (int c = 0; c < C_; ++c) x[c] = slab[c][col];
  int k0 = half ? 16 : 0, k1 = half ? 31 : 16;
  for (int k = k0; k < k1; ++k){
    float2 acc = make_float2(0.0f, 0.0f);
    int m = 0;
    #pragma unroll
    for (int j = 0; j < C_; ++j){
      float2 t = tw31[m];
      acc.x += x[j].x * t.x - x[j].y * t.y;
      acc.y += x[j].x * t.y + x[j].y * t.x;
      m += k; if (m >= C_) m -= C_;
    }
    float s = NORM_F / (base + dcs[k]);
    ybuf[k][col] = make_float2(acc.x * s, acc.y * s);
  }
  __syncthreads();
  #pragma unroll
  for (int k = 0; k < C_; ++k) x[k] = ybuf[k][col];
  for (int j = k0; j < k1; ++j){
    float2 acc = make_float2(0.0f, 0.0f);
    int m = 0;
    #pragma unroll
    for (int k = 0; k < C_; ++k){
      float2 t = tw31[m];               // conjugated use = inverse
      acc.x += x[k].x * t.x + x[k].y * t.y;
      acc.y += x[k].y * t.x - x[k].x * t.y;
      m += j; if (m >= C_) m -= C_;
    }
    slab[j][col] = acc;
  }
  __syncthreads();

  // H-FFT inverse
  for (int c = wv; c < C_; c += 4){
    float2 a = slab[c][lane], b = slab[c][lane+64];
    fft128_inv(a, b, twi, lane);
    slab[c][lane] = a; slab[c][lane+64] = b;
  }
  __syncthreads();
  for (int i = tid; i < CH_; i += 256)
    g[i] = ((float2*)slab)[i];
}

// K4: gather from A, inverse shuffle FFT-128 along W, write Z (Re->vol 2p, Im->vol 2p+1),
// fused X/G1/Q pointwise update.
__global__ __launch_bounds__(256) void kern_invW(const float2* __restrict__ A,
    float* __restrict__ Z, const float* __restrict__ Y, const float* __restrict__ inW,
    float* __restrict__ G1, float* __restrict__ Qo,
    float mu, int first, int last)
{
  int tid = threadIdx.x, lane = tid & 63;
  int r = blockIdx.x * 4 + (tid >> 6);
  int pair = r / CH_;
  int ch = r - pair * CH_;
  int c = ch >> 7, h = ch & (H_-1);

  float2 twi[7];
  make_tw(twi, lane, +1.0f, false);

  const float2* src = A + ((long)pair * W_) * CH_ + (long)c * H_ + h;
  float2 a = src[(long)lane * CH_];
  float2 b = src[(long)(lane + 64) * CH_];
  fft128_inv(a, b, twi, lane);

  long b0 = (((long)(2*pair) * C_ + c) * H_ + h) * W_;
  long b1 = b0 + (long)C_ * H_ * W_;
  float zs[4] = {a.x, a.y, b.x, b.y};
  long ps[4]  = {b0 + lane, b1 + lane, b0 + lane + 64, b1 + lane + 64};
  #pragma unroll
  for (int q = 0; q < 4; ++q){
    long p = ps[q];
    float z = zs[q];
    Z[p] = z;
    if (!last){
      float y = Y[p], iw = inW[p];
      float g1 = first ? 0.0f : G1[p];
      float x = (iw*y + mu*z - g1) / (iw + mu);
      float g1n = g1 + mu*(x - z);
      G1[p] = g1n;
      Qo[p] = x + g1n / (mu * RHO_F);
    }
  }
}

extern "C" void kernel_launch(void* const* d_in, const int* in_sizes, int n_in,
                              void* d_out, int out_size, void* d_ws, size_t ws_size,
                              hipStream_t stream)
{
  const float* Y   = (const float*)d_in[0];
  const float* inW = (const float*)d_in[1];
  float* Z = (float*)d_out;

  float* Q  = (float*)d_ws;
  float* G1 = Q  + TOTAL;
  float* Vh = G1 + TOTAL;
  float* Vv = Vh + TOTAL;
  float* Vs = Vv + TOTAL;
  float2* A = (float2*)(Vs + TOTAL);   // [2][128][31][128] complex = 8.1 MB

  float mu = 0.1f;
  for (int it = 0; it < 20; ++it){
    int first = (it == 0) ? 1 : 0;
    int last  = (it == 19) ? 1 : 0;
    float thr = 0.1f / mu;
    const float* Zs = first ? Y : (const float*)Z;
    const float* Qs = first ? Y : (const float*)Q;

    kern_V   <<<dim3(TOTAL/256),      dim3(256), 0, stream>>>(Zs, Vh, Vv, Vs, thr, first);
    kern_fwdW<<<dim3(2*CH_/4),        dim3(256), 0, stream>>>(Qs, Vh, Vv, Vs, A);
    kern_CH  <<<dim3(2*W_),           dim3(256), 0, stream>>>(A);
    kern_invW<<<dim3(2*CH_/4),        dim3(256), 0, stream>>>(A, Z, Y, inW, G1, Q, mu, first, last);

    mu *= 1.05f;
  }
}

// Round 3
// 954.772 us; speedup vs baseline: 3.6430x; 1.7215x over previous
//
#include <hip/hip_runtime.h>
#include <math.h>

#define N_ 4
#define C_ 31
#define H_ 128
#define W_ 128
#define TOTAL (N_*C_*H_*W_)
#define CPAD 32
#define PI_F 3.14159265358979f
#define RHO_F 1.05f
#define INV_RHO (1.0f/1.05f)
#define NORM2 (1.0f/16384.0f)    // 1/(128*128): W and H unnormalized fwd+inv pairs

__device__ __forceinline__ float2 cmul(float2 a, float2 b){
  return make_float2(a.x*b.x - a.y*b.y, a.x*b.y + a.y*b.x);
}
__device__ __forceinline__ float2 shflx(float2 v, int m){
  return make_float2(__shfl_xor(v.x, m, 64), __shfl_xor(v.y, m, 64));
}
__device__ __forceinline__ float shrinkf(float x, float t){
  return copysignf(fmaxf(fabsf(x) - t, 0.0f), x);
}

// Per-lane twiddles for the 64-lane shuffle FFT-128 (2 complex elems/lane).
__device__ __forceinline__ void make_tw(float2* tw, int t, float sgn, bool sel){
  float s, c;
  sincosf(sgn * 2.0f * PI_F * (float)t / 128.0f, &s, &c);
  tw[0] = make_float2(c, s);
  #pragma unroll
  for (int i = 1; i < 7; ++i){
    int sp = 64 >> i;
    float ang = (!sel || (t & sp)) ? sgn * 2.0f * PI_F * (float)(t & (sp-1)) / (float)(2*sp) : 0.0f;
    sincosf(ang, &s, &c);
    tw[i] = make_float2(c, s);
  }
}

// Forward DIF FFT-128; output at positions p: a->p=t, b->p=t+64, value X[bitrev7(p)].
__device__ __forceinline__ void fft128_fwd(float2& a, float2& b, const float2* twf, int t){
  float2 u = make_float2(a.x + b.x, a.y + b.y);
  float2 d = make_float2(a.x - b.x, a.y - b.y);
  float2 v = cmul(d, twf[0]);
  #pragma unroll
  for (int i = 1; i < 7; ++i){
    int sp = 64 >> i;
    bool up = (t & sp) != 0;
    float2 pu = shflx(u, sp);
    float2 du = up ? make_float2(pu.x - u.x, pu.y - u.y)
                   : make_float2(u.x + pu.x, u.y + pu.y);
    u = cmul(du, twf[i]);
    float2 pv = shflx(v, sp);
    float2 dv = up ? make_float2(pv.x - v.x, pv.y - v.y)
                   : make_float2(v.x + pv.x, v.y + pv.y);
    v = cmul(dv, twf[i]);
  }
  a = u; b = v;
}

// Inverse DIT FFT-128 (unnormalized): bit-reversed in, natural out.
__device__ __forceinline__ void fft128_inv(float2& a, float2& b, const float2* twi, int t){
  float2 u = a, v = b;
  #pragma unroll
  for (int i = 6; i >= 1; --i){
    int sp = 64 >> i;
    bool up = (t & sp) != 0;
    float2 pu = shflx(u, sp);
    float2 e  = up ? pu : u;
    float2 o  = up ? u  : pu;
    float2 wo = cmul(o, twi[i]);
    u = up ? make_float2(e.x - wo.x, e.y - wo.y)
           : make_float2(e.x + wo.x, e.y + wo.y);
    float2 pv = shflx(v, sp);
    float2 ev = up ? pv : v;
    float2 ov = up ? v  : pv;
    float2 wv = cmul(ov, twi[i]);
    v = up ? make_float2(ev.x - wv.x, ev.y - wv.y)
           : make_float2(ev.x + wv.x, ev.y + wv.y);
  }
  float2 tv = cmul(v, twi[0]);
  a = make_float2(u.x + tv.x, u.y + tv.y);
  b = make_float2(u.x - tv.x, u.y - tv.y);
}

// K1: V-field update.
__global__ __launch_bounds__(256) void kern_V(const float* __restrict__ Z,
    float* __restrict__ Vh, float* __restrict__ Vv, float* __restrict__ Vs,
    float thr, int first)
{
  int idx = blockIdx.x * 256 + threadIdx.x;
  int w = idx & (W_-1);
  int h = (idx >> 7) & (H_-1);
  int nc = idx >> 14;
  int c = nc % C_;
  float z = Z[idx];
  int iw1 = (idx - w) + ((w+1) & (W_-1));
  int ih1 = (idx - (h<<7)) + (((h+1) & (H_-1)) << 7);
  int ic1 = (c == C_-1) ? idx - (C_-1)*(H_*W_) : idx + H_*W_;
  float Dh = z - Z[iw1];
  float Dv = z - Z[ih1];
  float Ds = z - Z[ic1];
  if (first){
    Vh[idx] = shrinkf(Dh, thr);
    Vv[idx] = shrinkf(Dv, thr);
    Vs[idx] = shrinkf(Ds, thr);
  } else {
    const float a = 1.0f + INV_RHO;
    float vh = Vh[idx], vv = Vv[idx], vs = Vs[idx];
    Vh[idx] = shrinkf(a*Dh - vh*INV_RHO, thr) + (vh - Dh)*INV_RHO;
    Vv[idx] = shrinkf(a*Dv - vv*INV_RHO, thr) + (vv - Dv)*INV_RHO;
    Vs[idx] = shrinkf(a*Ds - vs*INV_RHO, thr) + (vs - Ds)*INV_RHO;
  }
}

// K2: numer (pair packed as complex) -> W-FFT per wave -> LDS transpose -> coalesced A store.
// Blocks: (pair, h, c-chunk of 8). A layout [pair][w][h][CPAD=32].
__global__ __launch_bounds__(512,4) void kern_fwdW(const float* __restrict__ Q,
    const float* __restrict__ Vh, const float* __restrict__ Vv, const float* __restrict__ Vs,
    float2* __restrict__ A)
{
  __shared__ float tre[8][129], tim[8][129];
  int tid = threadIdx.x, lane = tid & 63, r = tid >> 6;
  int b = blockIdx.x;
  int chunk = b & 3, h = (b >> 2) & (H_-1), pair = b >> 9;
  int c0 = chunk * 8, c = c0 + r;
  if (c < C_){
    float2 twf[7];
    make_tw(twf, lane, -1.0f, true);
    long base0 = (((long)(2*pair)*C_ + c)*H_ + h)*W_;
    long base1 = base0 + (long)C_*H_*W_;
    int hm1 = (h + H_-1) & (H_-1);
    long dv = ((long)hm1 - h) * W_;
    int cm1 = (c == 0) ? (C_-1) : (c-1);
    long dsd = ((long)cm1 - c) * H_ * W_;
    float2 ab[2];
    #pragma unroll
    for (int e = 0; e < 2; ++e){
      int w = lane + 64*e;
      int wm1 = (w + W_-1) & (W_-1);
      float re = Q[base0+w] + (Vh[base0+w] - Vh[base0+wm1])
               + (Vv[base0+w] - Vv[base0+dv+w]) + (Vs[base0+w] - Vs[base0+dsd+w]);
      float im = Q[base1+w] + (Vh[base1+w] - Vh[base1+wm1])
               + (Vv[base1+w] - Vv[base1+dv+w]) + (Vs[base1+w] - Vs[base1+dsd+w]);
      ab[e] = make_float2(re, im);
    }
    fft128_fwd(ab[0], ab[1], twf, lane);
    tre[r][lane]    = ab[0].x; tim[r][lane]    = ab[0].y;
    tre[r][lane+64] = ab[1].x; tim[r][lane+64] = ab[1].y;
  }
  __syncthreads();
  int ws = tid >> 2, q = tid & 3;
  long abase = (((long)pair*W_ + ws)*H_ + h)*CPAD + c0;
  int cA = 2*q;
  if (c0 + cA + 1 < C_){
    float4 v = make_float4(tre[cA][ws], tim[cA][ws], tre[cA+1][ws], tim[cA+1][ws]);
    *(float4*)(A + abase + cA) = v;
  } else if (c0 + cA < C_){
    A[abase + cA] = make_float2(tre[cA][ws], tim[cA][ws]);
  }
}

// K3: slab load -> H-FFT fwd (shuffle) -> 25-tap circulant solve along c -> H-FFT inv -> store.
// One block (1024 thr) per (pair, w). LDS slab [h][c] with c-stride 31 (odd: conflict-free).
__global__ __launch_bounds__(1024) void kern_CH(float2* __restrict__ A)
{
  __shared__ float2 slab[H_][C_];
  int tid = threadIdx.x, lane = tid & 63, wv = tid >> 6;
  int bid = blockIdx.x;                 // pair*128 + w
  int w = bid & (W_-1);
  float2* g = A + (long)bid * H_ * CPAD;
  float2* sl = &slab[0][0];

  for (int i = tid; i < H_*C_; i += 1024){
    int hh = i / C_;
    int cc = i - hh*C_;
    sl[i] = g[(hh << 5) + cc];
  }
  float2 twf[7], twi[7];
  make_tw(twf, lane, -1.0f, true);
  make_tw(twi, lane, +1.0f, false);
  __syncthreads();

  // H-FFT forward: 31 rows over 16 waves (2 rounds; disjoint rows, no sync needed between)
  #pragma unroll
  for (int rr = 0; rr < 2; ++rr){
    int c = wv + 16*rr;
    if (c < C_){
      float2 a = slab[lane][c], b = slab[lane+64][c];
      fft128_fwd(a, b, twf, lane);
      slab[lane][c] = a; slab[lane+64][c] = b;
    }
  }
  __syncthreads();

  // circulant conv along c: thread = (h-col, 4-c-block)
  {
    int col = tid & (H_-1), cb = tid >> 7, c0 = cb * 4;
    int fh = __brev(col) >> 25;
    int fw = __brev(w)   >> 25;
    float dh = 2.0f - 2.0f * cosf(2.0f * PI_F * (float)fh / 128.0f);
    float dw = 2.0f - 2.0f * cosf(2.0f * PI_F * (float)fw / 128.0f);
    float beta = 1.0f + dh + dw;
    float a2 = beta + 2.0f;
    float s  = sqrtf(a2*a2 - 4.0f);
    float rg = (a2 - s) * 0.5f;        // decay ratio <= 0.382
    float gt[13];
    gt[0] = NORM2 / s;
    #pragma unroll
    for (int t = 1; t < 13; ++t) gt[t] = gt[t-1] * rg;

    float2 win[28];
    #pragma unroll
    for (int i = 0; i < 28; ++i){
      int ci = c0 - 12 + i;
      if (ci < 0) ci += C_;
      if (ci >= C_) ci -= C_;
      win[i] = slab[col][ci];
    }
    float2 out[4];
    #pragma unroll
    for (int j = 0; j < 4; ++j){
      float ox = 0.0f, oy = 0.0f;
      #pragma unroll
      for (int t = -12; t <= 12; ++t){
        float gv = gt[t < 0 ? -t : t];
        float2 xv = win[j + 12 - t];
        ox += gv * xv.x;
        oy += gv * xv.y;
      }
      out[j] = make_float2(ox, oy);
    }
    __syncthreads();
    #pragma unroll
    for (int j = 0; j < 4; ++j){
      int c = c0 + j;
      if (c < C_) slab[col][c] = out[j];
    }
  }
  __syncthreads();

  // H-FFT inverse
  #pragma unroll
  for (int rr = 0; rr < 2; ++rr){
    int c = wv + 16*rr;
    if (c < C_){
      float2 a = slab[lane][c], b = slab[lane+64][c];
      fft128_inv(a, b, twi, lane);
      slab[lane][c] = a; slab[lane+64][c] = b;
    }
  }
  __syncthreads();
  for (int i = tid; i < H_*C_; i += 1024){
    int hh = i / C_;
    int cc = i - hh*C_;
    g[(hh << 5) + cc] = sl[i];
  }
}

// K4: coalesced A load -> LDS transpose -> inverse W-FFT per wave -> Z + fused X/G1/Q update.
__global__ __launch_bounds__(512,4) void kern_invW(const float2* __restrict__ A,
    float* __restrict__ Z, const float* __restrict__ Y, const float* __restrict__ inW,
    float* __restrict__ G1, float* __restrict__ Qo,
    float mu, int first, int last)
{
  __shared__ float tre[8][129], tim[8][129];
  int tid = threadIdx.x, lane = tid & 63, r = tid >> 6;
  int b = blockIdx.x;
  int chunk = b & 3, h = (b >> 2) & (H_-1), pair = b >> 9;
  int c0 = chunk * 8;
  {
    int ws = tid >> 2, q = tid & 3;
    long abase = (((long)pair*W_ + ws)*H_ + h)*CPAD + c0;
    int cA = 2*q;
    if (c0 + cA + 1 < C_){
      float4 v = *(const float4*)(A + abase + cA);
      tre[cA][ws] = v.x; tim[cA][ws] = v.y; tre[cA+1][ws] = v.z; tim[cA+1][ws] = v.w;
    } else if (c0 + cA < C_){
      float2 v = A[abase + cA];
      tre[cA][ws] = v.x; tim[cA][ws] = v.y;
    }
  }
  __syncthreads();
  int c = c0 + r;
  if (c >= C_) return;
  float2 twi[7];
  make_tw(twi, lane, +1.0f, false);
  float2 a  = make_float2(tre[r][lane],    tim[r][lane]);
  float2 bb = make_float2(tre[r][lane+64], tim[r][lane+64]);
  fft128_inv(a, bb, twi, lane);

  long base0 = (((long)(2*pair)*C_ + c)*H_ + h)*W_;
  long base1 = base0 + (long)C_*H_*W_;
  float zs[4] = {a.x, a.y, bb.x, bb.y};
  long ps[4]  = {base0 + lane, base1 + lane, base0 + lane + 64, base1 + lane + 64};
  #pragma unroll
  for (int qq = 0; qq < 4; ++qq){
    long p = ps[qq];
    float z = zs[qq];
    Z[p] = z;
    if (!last){
      float y = Y[p], iw = inW[p];
      float g1 = first ? 0.0f : G1[p];
      float x = (iw*y + mu*z - g1) / (iw + mu);
      float g1n = g1 + mu*(x - z);
      G1[p] = g1n;
      Qo[p] = x + g1n / (mu * RHO_F);
    }
  }
}

extern "C" void kernel_launch(void* const* d_in, const int* in_sizes, int n_in,
                              void* d_out, int out_size, void* d_ws, size_t ws_size,
                              hipStream_t stream)
{
  const float* Y   = (const float*)d_in[0];
  const float* inW = (const float*)d_in[1];
  float* Z = (float*)d_out;

  float* Q  = (float*)d_ws;
  float* G1 = Q  + TOTAL;
  float* Vh = G1 + TOTAL;
  float* Vv = Vh + TOTAL;
  float* Vs = Vv + TOTAL;
  float2* A = (float2*)(Vs + TOTAL);   // [2][128][128][32] float2 = 8.39 MB

  float mu = 0.1f;
  for (int it = 0; it < 20; ++it){
    int first = (it == 0) ? 1 : 0;
    int last  = (it == 19) ? 1 : 0;
    float thr = 0.1f / mu;
    const float* Zs = first ? Y : (const float*)Z;
    const float* Qs = first ? Y : (const float*)Q;

    kern_V   <<<dim3(TOTAL/256),   dim3(256),  0, stream>>>(Zs, Vh, Vv, Vs, thr, first);
    kern_fwdW<<<dim3(2*H_*4),      dim3(512),  0, stream>>>(Qs, Vh, Vv, Vs, A);
    kern_CH  <<<dim3(2*W_),        dim3(1024), 0, stream>>>(A);
    kern_invW<<<dim3(2*H_*4),      dim3(512),  0, stream>>>(A, Z, Y, inW, G1, Q, mu, first, last);

    mu *= 1.05f;
  }
}